// Round 5
// baseline (127.395 us; speedup 1.0000x reference)
//
#include <hip/hip_runtime.h>

typedef float f32x4 __attribute__((ext_vector_type(4)));
typedef float f32x16v __attribute__((ext_vector_type(16)));
typedef __bf16 bf16x4 __attribute__((ext_vector_type(4)));
typedef __bf16 bf16x8 __attribute__((ext_vector_type(8)));

// ws layout (bf16 elements): b2p[9216] @0, b3p[36864] @9216, c1p[1024] @46080
#define B2P_OFF 0
#define B3P_OFF 9216
#define C1P_OFF 46080

// ------------------------------------------------------------- pack_weights
// b2p frag f=t*2+p: lane l, j: oc=l&31, ic=(l>>5)*8+j              (32x32x16)
// b3p frag f=t*8+nt*2+p: lane l, j: oc=nt*16+(l&15), ic=(l>>4)*8+j (16x16x32)
// c1p (R19 mapping): A-frag = two horizontally-adjacent s_img cells.
__global__ __launch_bounds__(256) void pack_weights(
    const float* __restrict__ w1, const float* __restrict__ w2,
    const float* __restrict__ w3, __bf16* __restrict__ wsb) {
  int i = blockIdx.x * 256 + threadIdx.x;
  if (i < 9216) {
    int f = i >> 9, r = i & 511;
    int l = r >> 3, j = r & 7;
    int t = f >> 1, p = f & 1;
    int ky = t / 3, kx = t % 3;
    int oc = l & 31, ic = ((l >> 5) << 3) + j;
    float v = w2[oc * 144 + ic * 9 + ky * 3 + kx];
    __bf16 hi = (__bf16)v;
    wsb[B2P_OFF + i] = p ? (__bf16)(v - (float)hi) : hi;
  } else if (i < 9216 + 36864) {
    int q = i - 9216;
    int f = q >> 9, r = q & 511;
    int l = r >> 3, j = r & 7;
    int t = f >> 3, nt = (f >> 1) & 3, p = f & 1;
    int ky = t / 3, kx = t % 3;
    int oc = nt * 16 + (l & 15), ic = ((l >> 4) << 3) + j;
    float v = w3[oc * 288 + ic * 9 + ky * 3 + kx];
    __bf16 hi = (__bf16)v;
    wsb[B3P_OFF + q] = p ? (__bf16)(v - (float)hi) : hi;
  } else if (i < 9216 + 36864 + 1024) {
    int q = i - (9216 + 36864);
    int f = q >> 9, r = q & 511;
    int l = r >> 3, j = r & 7;
    int oc = l & 15, kg = l >> 4;
    int half = j >> 2, ic = j & 3;
    float v = 0.f;
    if (ic < 3) {
      if (f == 0) {
        if (kg < 3)            v = w1[oc * 27 + ic * 9 + kg * 3 + half];
        else if (half == 0)    v = w1[oc * 27 + ic * 9 + 0 * 3 + 2];
      } else {
        if (half == 0 && kg < 2) v = w1[oc * 27 + ic * 9 + (kg + 1) * 3 + 2];
      }
    }
    wsb[C1P_OFF + q] = (__bf16)v;
  }
}

// -------------------------------------------------------------- fused CNN
// R19 numerics; 256 threads; 4-barrier overlay layout (R3-validated):
//   region0 @0:    s_img (9280B) / s3 (8960B, overlays after barrier 2b)
//   region1 @9280: s2 (16128B)   / h3s (5120B stride-20, s2 dead in conv3)
// Round-5: issue-work reduction (accounting shows VALU 36K + LDS 40K + MFMA
// 27K clk/CU ~= the whole 110K-cycle kernel, pipes near-serial):
//  - conv1 A-frags are CONTIGUOUS 16B in s_img -> load directly (memcpy,
//    8B-aligned -> ds_read2_b64): 64->32 LDS instr/lane, repack moves gone.
//  - staging: 4x8B cell writes -> 2x16B writes.
// R1/R4 lesson: parallelism (more waves / dual-stream ILP) does NOT move
// per-image time. R2 lesson: keep (256,4) or VGPR spills (WRITE_SIZE guard).
__global__ __launch_bounds__(256, 4) void cnn_fused(
    const float* __restrict__ x, const __bf16* __restrict__ wsb,
    const float* __restrict__ b1, const float* __restrict__ b2,
    const float* __restrict__ b3,
    const float* __restrict__ fcw, const float* __restrict__ fcb,
    float* __restrict__ out) {
  __shared__ __align__(16) unsigned char smem[25408];
  __bf16* s_img = (__bf16*)smem;                 // [0, 9280)
  __bf16* s2b   = (__bf16*)(smem + 9280);        // [9280, 25408)
  __bf16* s3b   = (__bf16*)smem;                 // [0, 8960)  (s_img dead)
  float*  h3s   = (float*)(smem + 9280);         // [9280, 14400) (s2 dead)

  const __bf16* b2p = wsb + B2P_OFF;
  const __bf16* b3p = wsb + B3P_OFF;
  const __bf16* c1p = wsb + C1P_OFF;

  const int tid = threadIdx.x;
  const int img = blockIdx.x;
  const int w = tid >> 6, lane = tid & 63;

  // ---- phase 1: halo zero (132 cells) + end pad + float4 staging
  if (tid < 132) {
    int row, col;
    if (tid < 34)       { row = 0;        col = tid; }
    else if (tid < 68)  { row = 33;       col = tid - 34; }
    else if (tid < 100) { row = tid - 67; col = 0; }
    else                { row = tid - 99; col = 33; }
    *(unsigned long long*)&s_img[(row * 34 + col) * 4] = 0ull;
  } else if (tid >= 248 && tid < 252) {
    *(unsigned long long*)&s_img[4624 + (tid - 248) * 4] = 0ull;  // pad
  }
  {
    const float* xg = x + img * 3072;
    const int r = tid * 4;
    const int y = r >> 5, xx = r & 31;
    const f32x4 c0 = *(const f32x4*)&xg[r];
    const f32x4 c1 = *(const f32x4*)&xg[r + 1024];
    const f32x4 c2 = *(const f32x4*)&xg[r + 2048];
    bf16x4 pk[4];
    #pragma unroll
    for (int k = 0; k < 4; ++k) {
      pk[k].x = (__bf16)c0[k];
      pk[k].y = (__bf16)c1[k];
      pk[k].z = (__bf16)c2[k];
      pk[k].w = (__bf16)0.f;
    }
    // cells (y+1, xx+1 .. xx+4) are consecutive: two 16B writes (8B-aligned)
    const int base = ((y + 1) * 34 + (xx + 1)) * 4;
    __builtin_memcpy(&s_img[base],     &pk[0], 16);
    __builtin_memcpy(&s_img[base + 8], &pk[2], 16);
  }
  const bf16x8 B1h = *(const bf16x8*)(c1p + lane * 8);
  const bf16x8 B2h = *(const bf16x8*)(c1p + 512 + lane * 8);
  __syncthreads();                       // barrier 1: staging complete

  // ---- conv1: select-free A-build; A-frag = one contiguous 16B LDS load
  float pooled[16];
  {
    const int xm = lane & 15, kg = lane >> 4;
    const int d1r = (kg == 3) ? 0 : kg;
    const int d1c = (kg == 3) ? 2 : 0;
    const int d2r = (kg == 0) ? 1 : 2;
    const int dd1 = d1r * 34 + d1c;
    const int dd2 = d2r * 34 + 2;
    #pragma unroll
    for (int p = 0; p < 4; ++p) {
      f32x4 acc[2][2];
      #pragma unroll
      for (int ys = 0; ys < 2; ++ys)
        #pragma unroll
        for (int xh = 0; xh < 2; ++xh)
          #pragma unroll
          for (int r = 0; r < 4; ++r) acc[ys][xh][r] = 0.f;
      #pragma unroll
      for (int ys = 0; ys < 2; ++ys) {
        const int yqg = w * 8 + p * 2 + ys;
        #pragma unroll
        for (int xh = 0; xh < 2; ++xh) {
          const int cb = yqg * 34 + xh * 16 + xm;
          bf16x8 A1, A2;
          __builtin_memcpy(&A1, &s_img[(cb + dd1) * 4], 16);
          __builtin_memcpy(&A2, &s_img[(cb + dd2) * 4], 16);
          acc[ys][xh] = __builtin_amdgcn_mfma_f32_16x16x32_bf16(A1, B1h, acc[ys][xh], 0, 0, 0);
          acc[ys][xh] = __builtin_amdgcn_mfma_f32_16x16x32_bf16(A2, B2h, acc[ys][xh], 0, 0, 0);
        }
      }
      #pragma unroll
      for (int xh = 0; xh < 2; ++xh)
        #pragma unroll
        for (int xp2 = 0; xp2 < 2; ++xp2) {
          const float v0 = fmaxf(acc[0][xh][xp2 * 2], acc[0][xh][xp2 * 2 + 1]);
          const float v1 = fmaxf(acc[1][xh][xp2 * 2], acc[1][xh][xp2 * 2 + 1]);
          pooled[p * 4 + xh * 2 + xp2] = fmaxf(v0, v1);
        }
    }
  }
  // (no barrier: s2 @9280 is disjoint from s_img @0)

  // ---- h1 (bias+relu, bf16 hi only) -> s2 (row stride 448, cell 24)
  if (tid < 68) {
    int row, col;
    if (tid < 18)      { row = 0;       col = tid; }
    else if (tid < 36) { row = 17;      col = tid - 18; }
    else if (tid < 52) { row = tid - 35; col = 0; }
    else               { row = tid - 51; col = 17; }
    unsigned long long* p = (unsigned long long*)&s2b[row * 448 + col * 24];
    p[0] = 0ull; p[1] = 0ull; p[2] = 0ull; p[3] = 0ull;
  }
  {
    const int oc = lane & 15, quad = lane >> 4;
    const float bias = b1[oc];
    #pragma unroll
    for (int p = 0; p < 4; ++p)
      #pragma unroll
      for (int xh = 0; xh < 2; ++xh)
        #pragma unroll
        for (int xp2 = 0; xp2 < 2; ++xp2) {
          const float v = fmaxf(pooled[p * 4 + xh * 2 + xp2] + bias, 0.f);
          const int py = w * 4 + p, px = xh * 8 + quad * 2 + xp2;
          s2b[(py + 1) * 448 + (px + 1) * 24 + oc] = (__bf16)v;
        }
  }
  bf16x8 Bf[9];
  #pragma unroll
  for (int t = 0; t < 9; ++t)
    Bf[t] = *(const bf16x8*)(b2p + (t * 2) * 512 + lane * 8);
  __syncthreads();                       // barrier 2b: h1 complete
                                         // (also: all s_img reads done -> s3 may overlay)

  // ---- conv2 (1-term), y-halves sequential
  float pooled2[8];
  {
    const unsigned short* s2 = (const unsigned short*)s2b;
    const int xm = lane & 15, yoff = (lane >> 4) & 1, kh = lane >> 5;
    #pragma unroll
    for (int i2 = 0; i2 < 2; ++i2) {
      f32x16v acc;
      #pragma unroll
      for (int r = 0; r < 16; ++r) acc[r] = 0.f;
      const int rbase = (4 * w + yoff + 2 * i2) * 448;
      #pragma unroll
      for (int t = 0; t < 9; ++t) {
        const int ky = t / 3, kx = t % 3;
        const int ro = rbase + ky * 448 + (xm + kx) * 24 + kh * 8;
        bf16x8 ah = *(const bf16x8*)&s2[ro];
        acc = __builtin_amdgcn_mfma_f32_32x32x16_bf16(ah, Bf[t], acc, 0, 0, 0);
      }
      #pragma unroll
      for (int bq = 0; bq < 2; ++bq)
        #pragma unroll
        for (int rq = 0; rq < 2; ++rq) {
          const int r0 = bq * 4 + rq * 2;
          pooled2[i2 * 4 + bq * 2 + rq] =
              fmaxf(fmaxf(acc[r0], acc[r0 + 1]), fmaxf(acc[r0 + 8], acc[r0 + 9]));
        }
    }
  }
  // (no barrier: s3 @0 is disjoint from s2 @9280; s_img dead since barrier 2b)

  // ---- h2 (bias+relu, bf16 hi only) -> s3 (row stride 448, cell 40)
  if (tid < 36) {
    int row, col;
    if (tid < 10)      { row = 0;       col = tid; }
    else if (tid < 20) { row = 9;       col = tid - 10; }
    else if (tid < 28) { row = tid - 19; col = 0; }
    else               { row = tid - 27; col = 9; }
    unsigned long long* p = (unsigned long long*)&s3b[row * 448 + col * 40];
    #pragma unroll
    for (int u = 0; u < 8; ++u) p[u] = 0ull;
  }
  {
    const int oc = lane & 31, hh = lane >> 5;
    const float bias = b2[oc];
    #pragma unroll
    for (int i2 = 0; i2 < 2; ++i2)
      #pragma unroll
      for (int bq = 0; bq < 2; ++bq)
        #pragma unroll
        for (int rq = 0; rq < 2; ++rq) {
          const float v = fmaxf(pooled2[i2 * 4 + bq * 2 + rq] + bias, 0.f);
          const int py = 2 * w + i2, px = 2 * hh + 4 * bq + rq;
          s3b[(py + 1) * 448 + (px + 1) * 40 + oc] = (__bf16)v;
        }
  }
  __syncthreads();                       // barrier 3b: h2 complete
                                         // (also: all s2 reads done -> h3s may overlay)

  // ---- conv3 (wave = nt = oc-tile), 1-term; h3s @9280 (over dead s2 head)
  {
    const unsigned short* s3 = (const unsigned short*)s3b;
    const int nt = w;
    bf16x8 Bt[9];
    #pragma unroll
    for (int t = 0; t < 9; ++t)
      Bt[t] = *(const bf16x8*)(b3p + (t * 8 + nt * 2) * 512 + lane * 8);
    const int m = lane & 15, quad = lane >> 4;
    const int xm = m & 7, yoff = m >> 3;
    f32x4 acc[4];
    #pragma unroll
    for (int mt = 0; mt < 4; ++mt)
      #pragma unroll
      for (int r = 0; r < 4; ++r) acc[mt][r] = 0.f;
    #pragma unroll
    for (int t = 0; t < 9; ++t) {
      const int ky = t / 3, kx = t % 3;
      #pragma unroll
      for (int mt = 0; mt < 4; ++mt) {
        const int ro = (2 * mt + yoff + ky) * 448 + (xm + kx) * 40 + quad * 8;
        bf16x8 ah = *(const bf16x8*)&s3[ro];
        acc[mt] = __builtin_amdgcn_mfma_f32_16x16x32_bf16(ah, Bt[t], acc[mt], 0, 0, 0);
      }
    }
    const int ocl = lane & 15;
    #pragma unroll
    for (int mt = 0; mt < 4; ++mt) {
      float p0 = fmaxf(acc[mt][0], acc[mt][1]);
      float p1 = fmaxf(acc[mt][2], acc[mt][3]);
      p0 = fmaxf(p0, __shfl_xor(p0, 32, 64));
      p1 = fmaxf(p1, __shfl_xor(p1, 32, 64));
      if (quad < 2) {
        const int oc = nt * 16 + ocl;
        const float bias = b3[oc];
        const int base = oc * 20 + mt * 4 + (quad & 1) * 2;   // stride 20: bank-spread
        h3s[base]     = fmaxf(p0 + bias, 0.f);
        h3s[base + 1] = fmaxf(p1 + bias, 0.f);
      }
    }
  }
  __syncthreads();                       // barrier 4: h3 complete

  // ---- fc: lane owns 16 contiguous h-elements (oc=lane); LDS stride 20
  {
    f32x4 hv[4];
    #pragma unroll
    for (int k = 0; k < 4; ++k) hv[k] = *(const f32x4*)&h3s[lane * 20 + k * 4];
    for (int j = w; j < 10; j += 4) {
      const f32x4* fw4 = (const f32x4*)&fcw[j * 1024 + lane * 16];
      float dot = 0.f;
      #pragma unroll
      for (int k = 0; k < 4; ++k) {
        const f32x4 fv = fw4[k];
        dot = fmaf(hv[k][0], fv[0], dot);
        dot = fmaf(hv[k][1], fv[1], dot);
        dot = fmaf(hv[k][2], fv[2], dot);
        dot = fmaf(hv[k][3], fv[3], dot);
      }
      #pragma unroll
      for (int s = 32; s > 0; s >>= 1) dot += __shfl_xor(dot, s, 64);
      if (lane == 0) out[img * 10 + j] = dot + fcb[j];
    }
  }
}

// -------------------------------------------------------------------- launch
extern "C" void kernel_launch(void* const* d_in, const int* in_sizes, int n_in,
                              void* d_out, int out_size, void* d_ws, size_t ws_size,
                              hipStream_t stream) {
  const float* x   = (const float*)d_in[0];
  const float* w1  = (const float*)d_in[1];
  const float* b1  = (const float*)d_in[2];
  const float* w2  = (const float*)d_in[3];
  const float* b2  = (const float*)d_in[4];
  const float* w3  = (const float*)d_in[5];
  const float* b3  = (const float*)d_in[6];
  const float* fcw = (const float*)d_in[7];
  const float* fcb = (const float*)d_in[8];
  __bf16* wsb = (__bf16*)d_ws;
  float* out = (float*)d_out;

  hipLaunchKernelGGL(pack_weights, dim3(184), dim3(256), 0, stream, w1, w2, w3, wsb);
  hipLaunchKernelGGL(cnn_fused, dim3(4096), dim3(256), 0, stream,
                     x, wsb, b1, b2, b3, fcw, fcb, out);
}

// Round 6
// 124.658 us; speedup vs baseline: 1.0220x; 1.0220x over previous
//
#include <hip/hip_runtime.h>

typedef float f32x4 __attribute__((ext_vector_type(4)));
typedef float f32x16v __attribute__((ext_vector_type(16)));
typedef __bf16 bf16x4 __attribute__((ext_vector_type(4)));
typedef __bf16 bf16x8 __attribute__((ext_vector_type(8)));

// ws layout (bf16 elements): b2p[9216] @0, b3n[18432] @9216, c1p[1024] @46080
#define B2P_OFF 0
#define B3P_OFF 9216
#define C1P_OFF 46080

// ------------------------------------------------------------- pack_weights
// b2p frag f=t*2+p: lane l, j: oc=l&31, ic=(l>>5)*8+j               (32x32x16)
// b3n frag f=t*4+h*2+nt: lane l, j: oc=nt*32+(l&31), ic=h*16+(l>>5)*8+j
//     (32x32x16 B-layout; hi-only — conv3 never read the lo fragments)
// c1p (R19 mapping): A-frag = two horizontally-adjacent s_img cells.
__global__ __launch_bounds__(256) void pack_weights(
    const float* __restrict__ w1, const float* __restrict__ w2,
    const float* __restrict__ w3, __bf16* __restrict__ wsb) {
  int i = blockIdx.x * 256 + threadIdx.x;
  if (i < 9216) {
    int f = i >> 9, r = i & 511;
    int l = r >> 3, j = r & 7;
    int t = f >> 1, p = f & 1;
    int ky = t / 3, kx = t % 3;
    int oc = l & 31, ic = ((l >> 5) << 3) + j;
    float v = w2[oc * 144 + ic * 9 + ky * 3 + kx];
    __bf16 hi = (__bf16)v;
    wsb[B2P_OFF + i] = p ? (__bf16)(v - (float)hi) : hi;
  } else if (i < 9216 + 18432) {
    int q = i - 9216;
    int f = q >> 9, r = q & 511;
    int l = r >> 3, j = r & 7;
    int t = f >> 2, h = (f >> 1) & 1, nt = f & 1;
    int ky = t / 3, kx = t % 3;
    int oc = nt * 32 + (l & 31);
    int ic = h * 16 + ((l >> 5) << 3) + j;
    wsb[B3P_OFF + q] = (__bf16)w3[oc * 288 + ic * 9 + ky * 3 + kx];
  } else if (i >= 46080 && i < 47104) {
    int q = i - 46080;
    int f = q >> 9, r = q & 511;
    int l = r >> 3, j = r & 7;
    int oc = l & 15, kg = l >> 4;
    int half = j >> 2, ic = j & 3;
    float v = 0.f;
    if (ic < 3) {
      if (f == 0) {
        if (kg < 3)            v = w1[oc * 27 + ic * 9 + kg * 3 + half];
        else if (half == 0)    v = w1[oc * 27 + ic * 9 + 0 * 3 + 2];
      } else {
        if (half == 0 && kg < 2) v = w1[oc * 27 + ic * 9 + (kg + 1) * 3 + 2];
      }
    }
    wsb[C1P_OFF + q] = (__bf16)v;
  }
}

// -------------------------------------------------------------- fused CNN
// R19 numerics; 256 threads; 4-barrier overlay layout (R3-validated):
//   region0 @0:    s_img (9280B) / s3 (8960B, overlays after barrier 2b)
//   region1 @9280: s2 (16128B)   / h3s (5120B stride-20, s2 dead in conv3)
// Round-6: LDS BYTE reduction. Model (explains R1/R4/R5 nulls): LDS pipe is
// per-CU byte-throughput-bound (~85B/cyc for b128) — ~5.3K LDS cycles/block
// x16 blocks ~= 75% of the kernel. conv3 was the top consumer (147KB/block
// via 16x16x32: 16B A-frag per 16K FLOP). Switch conv3 to 32x32x16 (16B
// A-frag per 32K FLOP): 36->18 MFMA, reads halved, AND the 32x32 C-tile
// keeps each 2x2 pool window inside one lane -> 8 shfl_xor (LDS pipe!) and
// half-idle writes eliminated; all 64 lanes write 4 pooled values.
// R1/R4 lesson: more waves / more ILP don't move per-image time.
// R2 lesson: watch WRITE_SIZE for VGPR spill (Bt[18] = 72 VGPRs).
__global__ __launch_bounds__(256, 4) void cnn_fused(
    const float* __restrict__ x, const __bf16* __restrict__ wsb,
    const float* __restrict__ b1, const float* __restrict__ b2,
    const float* __restrict__ b3,
    const float* __restrict__ fcw, const float* __restrict__ fcb,
    float* __restrict__ out) {
  __shared__ __align__(16) unsigned char smem[25408];
  __bf16* s_img = (__bf16*)smem;                 // [0, 9280)
  __bf16* s2b   = (__bf16*)(smem + 9280);        // [9280, 25408)
  __bf16* s3b   = (__bf16*)smem;                 // [0, 8960)  (s_img dead)
  float*  h3s   = (float*)(smem + 9280);         // [9280, 14400) (s2 dead)

  const __bf16* b2p = wsb + B2P_OFF;
  const __bf16* b3p = wsb + B3P_OFF;
  const __bf16* c1p = wsb + C1P_OFF;

  const int tid = threadIdx.x;
  const int img = blockIdx.x;
  const int w = tid >> 6, lane = tid & 63;

  // ---- phase 1: halo zero (132 cells) + end pad + float4 staging
  if (tid < 132) {
    int row, col;
    if (tid < 34)       { row = 0;        col = tid; }
    else if (tid < 68)  { row = 33;       col = tid - 34; }
    else if (tid < 100) { row = tid - 67; col = 0; }
    else                { row = tid - 99; col = 33; }
    *(unsigned long long*)&s_img[(row * 34 + col) * 4] = 0ull;
  } else if (tid >= 248 && tid < 252) {
    *(unsigned long long*)&s_img[4624 + (tid - 248) * 4] = 0ull;  // pad
  }
  {
    const float* xg = x + img * 3072;
    const int r = tid * 4;
    const int y = r >> 5, xx = r & 31;
    const f32x4 c0 = *(const f32x4*)&xg[r];
    const f32x4 c1 = *(const f32x4*)&xg[r + 1024];
    const f32x4 c2 = *(const f32x4*)&xg[r + 2048];
    bf16x4 pk[4];
    #pragma unroll
    for (int k = 0; k < 4; ++k) {
      pk[k].x = (__bf16)c0[k];
      pk[k].y = (__bf16)c1[k];
      pk[k].z = (__bf16)c2[k];
      pk[k].w = (__bf16)0.f;
    }
    // cells (y+1, xx+1 .. xx+4) are consecutive: two 16B writes (8B-aligned)
    const int base = ((y + 1) * 34 + (xx + 1)) * 4;
    __builtin_memcpy(&s_img[base],     &pk[0], 16);
    __builtin_memcpy(&s_img[base + 8], &pk[2], 16);
  }
  const bf16x8 B1h = *(const bf16x8*)(c1p + lane * 8);
  const bf16x8 B2h = *(const bf16x8*)(c1p + 512 + lane * 8);
  __syncthreads();                       // barrier 1: staging complete

  // ---- conv1: select-free A-build; A-frag = one contiguous 16B LDS load
  float pooled[16];
  {
    const int xm = lane & 15, kg = lane >> 4;
    const int d1r = (kg == 3) ? 0 : kg;
    const int d1c = (kg == 3) ? 2 : 0;
    const int d2r = (kg == 0) ? 1 : 2;
    const int dd1 = d1r * 34 + d1c;
    const int dd2 = d2r * 34 + 2;
    #pragma unroll
    for (int p = 0; p < 4; ++p) {
      f32x4 acc[2][2];
      #pragma unroll
      for (int ys = 0; ys < 2; ++ys)
        #pragma unroll
        for (int xh = 0; xh < 2; ++xh)
          #pragma unroll
          for (int r = 0; r < 4; ++r) acc[ys][xh][r] = 0.f;
      #pragma unroll
      for (int ys = 0; ys < 2; ++ys) {
        const int yqg = w * 8 + p * 2 + ys;
        #pragma unroll
        for (int xh = 0; xh < 2; ++xh) {
          const int cb = yqg * 34 + xh * 16 + xm;
          bf16x8 A1, A2;
          __builtin_memcpy(&A1, &s_img[(cb + dd1) * 4], 16);
          __builtin_memcpy(&A2, &s_img[(cb + dd2) * 4], 16);
          acc[ys][xh] = __builtin_amdgcn_mfma_f32_16x16x32_bf16(A1, B1h, acc[ys][xh], 0, 0, 0);
          acc[ys][xh] = __builtin_amdgcn_mfma_f32_16x16x32_bf16(A2, B2h, acc[ys][xh], 0, 0, 0);
        }
      }
      #pragma unroll
      for (int xh = 0; xh < 2; ++xh)
        #pragma unroll
        for (int xp2 = 0; xp2 < 2; ++xp2) {
          const float v0 = fmaxf(acc[0][xh][xp2 * 2], acc[0][xh][xp2 * 2 + 1]);
          const float v1 = fmaxf(acc[1][xh][xp2 * 2], acc[1][xh][xp2 * 2 + 1]);
          pooled[p * 4 + xh * 2 + xp2] = fmaxf(v0, v1);
        }
    }
  }
  // (no barrier: s2 @9280 is disjoint from s_img @0)

  // ---- h1 (bias+relu, bf16 hi only) -> s2 (row stride 448, cell 24)
  if (tid < 68) {
    int row, col;
    if (tid < 18)      { row = 0;       col = tid; }
    else if (tid < 36) { row = 17;      col = tid - 18; }
    else if (tid < 52) { row = tid - 35; col = 0; }
    else               { row = tid - 51; col = 17; }
    unsigned long long* p = (unsigned long long*)&s2b[row * 448 + col * 24];
    p[0] = 0ull; p[1] = 0ull; p[2] = 0ull; p[3] = 0ull;
  }
  {
    const int oc = lane & 15, quad = lane >> 4;
    const float bias = b1[oc];
    #pragma unroll
    for (int p = 0; p < 4; ++p)
      #pragma unroll
      for (int xh = 0; xh < 2; ++xh)
        #pragma unroll
        for (int xp2 = 0; xp2 < 2; ++xp2) {
          const float v = fmaxf(pooled[p * 4 + xh * 2 + xp2] + bias, 0.f);
          const int py = w * 4 + p, px = xh * 8 + quad * 2 + xp2;
          s2b[(py + 1) * 448 + (px + 1) * 24 + oc] = (__bf16)v;
        }
  }
  bf16x8 Bf[9];
  #pragma unroll
  for (int t = 0; t < 9; ++t)
    Bf[t] = *(const bf16x8*)(b2p + (t * 2) * 512 + lane * 8);
  __syncthreads();                       // barrier 2b: h1 complete
                                         // (also: all s_img reads done -> s3 may overlay)

  // ---- conv2 (1-term), y-halves sequential
  float pooled2[8];
  {
    const unsigned short* s2 = (const unsigned short*)s2b;
    const int xm = lane & 15, yoff = (lane >> 4) & 1, kh = lane >> 5;
    #pragma unroll
    for (int i2 = 0; i2 < 2; ++i2) {
      f32x16v acc;
      #pragma unroll
      for (int r = 0; r < 16; ++r) acc[r] = 0.f;
      const int rbase = (4 * w + yoff + 2 * i2) * 448;
      #pragma unroll
      for (int t = 0; t < 9; ++t) {
        const int ky = t / 3, kx = t % 3;
        const int ro = rbase + ky * 448 + (xm + kx) * 24 + kh * 8;
        bf16x8 ah = *(const bf16x8*)&s2[ro];
        acc = __builtin_amdgcn_mfma_f32_32x32x16_bf16(ah, Bf[t], acc, 0, 0, 0);
      }
      #pragma unroll
      for (int bq = 0; bq < 2; ++bq)
        #pragma unroll
        for (int rq = 0; rq < 2; ++rq) {
          const int r0 = bq * 4 + rq * 2;
          pooled2[i2 * 4 + bq * 2 + rq] =
              fmaxf(fmaxf(acc[r0], acc[r0 + 1]), fmaxf(acc[r0 + 8], acc[r0 + 9]));
        }
    }
  }
  // (no barrier: s3 @0 is disjoint from s2 @9280; s_img dead since barrier 2b)

  // ---- h2 (bias+relu, bf16 hi only) -> s3 (row stride 448, cell 40)
  if (tid < 36) {
    int row, col;
    if (tid < 10)      { row = 0;       col = tid; }
    else if (tid < 20) { row = 9;       col = tid - 10; }
    else if (tid < 28) { row = tid - 19; col = 0; }
    else               { row = tid - 27; col = 9; }
    unsigned long long* p = (unsigned long long*)&s3b[row * 448 + col * 40];
    #pragma unroll
    for (int u = 0; u < 8; ++u) p[u] = 0ull;
  }
  {
    const int oc = lane & 31, hh = lane >> 5;
    const float bias = b2[oc];
    #pragma unroll
    for (int i2 = 0; i2 < 2; ++i2)
      #pragma unroll
      for (int bq = 0; bq < 2; ++bq)
        #pragma unroll
        for (int rq = 0; rq < 2; ++rq) {
          const float v = fmaxf(pooled2[i2 * 4 + bq * 2 + rq] + bias, 0.f);
          const int py = 2 * w + i2, px = 2 * hh + 4 * bq + rq;
          s3b[(py + 1) * 448 + (px + 1) * 40 + oc] = (__bf16)v;
        }
  }
  __syncthreads();                       // barrier 3b: h2 complete
                                         // (also: all s2 reads done -> h3s may overlay)

  // ---- conv3 as 32x32x16: wave = (mtile=w>>1, ntile=w&1); 18 reads+18 MFMA
  // A-frag: lane m=l&31 -> spatial (py=m>>3, px=m&7); k=(l>>5)*8+j -> ch.
  // C 32x32: col=lane&31=oc_local, row=(reg&3)+8*(reg>>2)+4*(lane>>5) = M.
  // Each 2x2 pool window lives in ONE lane's regs -> no shfl, all lanes write.
  {
    const unsigned short* s3 = (const unsigned short*)s3b;
    const int mtile = w >> 1, ntile = w & 1;
    bf16x8 Bt[18];
    #pragma unroll
    for (int t = 0; t < 9; ++t)
      #pragma unroll
      for (int h = 0; h < 2; ++h)
        Bt[t * 2 + h] = *(const bf16x8*)(b3p + (t * 4 + h * 2 + ntile) * 512 + lane * 8);
    const int m = lane & 31, half = lane >> 5;
    const int py = m >> 3, px = m & 7;
    f32x16v acc;
    #pragma unroll
    for (int r = 0; r < 16; ++r) acc[r] = 0.f;
    #pragma unroll
    for (int t = 0; t < 9; ++t) {
      const int ky = t / 3, kx = t % 3;
      const int ro = (mtile * 4 + py + ky) * 448 + (px + kx) * 40 + half * 8;
      bf16x8 a0 = *(const bf16x8*)&s3[ro];        // ch 0-15  (k-half by lane)
      bf16x8 a1 = *(const bf16x8*)&s3[ro + 16];   // ch 16-31
      acc = __builtin_amdgcn_mfma_f32_32x32x16_bf16(a0, Bt[t * 2 + 0], acc, 0, 0, 0);
      acc = __builtin_amdgcn_mfma_f32_32x32x16_bf16(a1, Bt[t * 2 + 1], acc, 0, 0, 0);
    }
    const int oc = ntile * 32 + (lane & 31);
    const float bias = b3[oc];
    // rows held by this lane: row = (reg&3) + 8*(reg>>2) + 4*half
    //   -> spatial py_loc = reg>>2, px = (reg&3) + 4*half.
    // pooled (i = py_loc>>1, jq = (reg&3)>>1): regs {8i+2jq, +1, +4, +5}.
    #pragma unroll
    for (int i = 0; i < 2; ++i)
      #pragma unroll
      for (int jq = 0; jq < 2; ++jq) {
        const int r0 = 8 * i + 2 * jq;
        const float v = fmaxf(fmaxf(acc[r0], acc[r0 + 1]),
                              fmaxf(acc[r0 + 4], acc[r0 + 5]));
        const int gy = mtile * 2 + i, gx = 2 * half + jq;
        h3s[oc * 20 + gy * 4 + gx] = fmaxf(v + bias, 0.f);
      }
  }
  __syncthreads();                       // barrier 4: h3 complete

  // ---- fc: lane owns 16 contiguous h-elements (oc=lane); LDS stride 20
  {
    f32x4 hv[4];
    #pragma unroll
    for (int k = 0; k < 4; ++k) hv[k] = *(const f32x4*)&h3s[lane * 20 + k * 4];
    for (int j = w; j < 10; j += 4) {
      const f32x4* fw4 = (const f32x4*)&fcw[j * 1024 + lane * 16];
      float dot = 0.f;
      #pragma unroll
      for (int k = 0; k < 4; ++k) {
        const f32x4 fv = fw4[k];
        dot = fmaf(hv[k][0], fv[0], dot);
        dot = fmaf(hv[k][1], fv[1], dot);
        dot = fmaf(hv[k][2], fv[2], dot);
        dot = fmaf(hv[k][3], fv[3], dot);
      }
      #pragma unroll
      for (int s = 32; s > 0; s >>= 1) dot += __shfl_xor(dot, s, 64);
      if (lane == 0) out[img * 10 + j] = dot + fcb[j];
    }
  }
}

// -------------------------------------------------------------------- launch
extern "C" void kernel_launch(void* const* d_in, const int* in_sizes, int n_in,
                              void* d_out, int out_size, void* d_ws, size_t ws_size,
                              hipStream_t stream) {
  const float* x   = (const float*)d_in[0];
  const float* w1  = (const float*)d_in[1];
  const float* b1  = (const float*)d_in[2];
  const float* w2  = (const float*)d_in[3];
  const float* b2  = (const float*)d_in[4];
  const float* w3  = (const float*)d_in[5];
  const float* b3  = (const float*)d_in[6];
  const float* fcw = (const float*)d_in[7];
  const float* fcb = (const float*)d_in[8];
  __bf16* wsb = (__bf16*)d_ws;
  float* out = (float*)d_out;

  hipLaunchKernelGGL(pack_weights, dim3(184), dim3(256), 0, stream, w1, w2, w3, wsb);
  hipLaunchKernelGGL(cnn_fused, dim3(4096), dim3(256), 0, stream,
                     x, wsb, b1, b2, b3, fcw, fcb, out);
}